// Round 7
// baseline (1302.556 us; speedup 1.0000x reference)
//
#include <hip/hip_runtime.h>

#define N_NODES 2048
#define C_CH    128
#define N_SPEC  10

// --- symmetric-reduced coefficient page per (species, channel) ---------------
// Layout: main[219][8] (monomial-major, i=0..7) | tail[219] (i==8), pad to 2048.
// Monomial order: m=0..164 sorted triples a<=b<=j (lex), 165..209 sorted pairs
// a<=b (lex), 210..218 singles a.
#define PAGE2   2048
#define MAIN_F  1752          // 219*8

#define CG_OFF_B  (256 * 1024)
#define CG_BYTES  ((size_t)N_SPEC * C_CH * PAGE2 * 4)

struct Params {
    const float* U3[3]; const float* W3[3];
    const float* U2[3]; const float* W2[3];
    const float* U1[3]; const float* W1[3];
};

// ---------------------------------------------------------------------------
// Kernel 1 (fused prep): blocks 0..1199 build coefficient pages with the U
// symmetrization folded into the LDS staging (bit-identical add order to the
// old usym+coef pair); block 1200 buckets nodes by species.
// ---------------------------------------------------------------------------
template <int ORD, int MUL, int IRD, int IOFF, int MOFF>
__device__ inline void coefRegion3(const float* __restrict__ u,   // full U tensor
                                   const float* __restrict__ W,   // [spec][MUL][C]
                                   int s, int row0, int rows, int c0,
                                   float* __restrict__ Cg,
                                   float* __restrict__ sU, float* __restrict__ sW) {
    const int tid = threadIdx.x;
    const int mi  = MUL * IRD;
    const int nfl = rows * mi;
    // stage symmetrized-U chunk: sU[rr*mi + k*IRD + il]
    for (int f = tid; f < nfl; f += 128) {
        const int rr  = f / mi;
        const int rem = f - rr * mi;          // k*IRD + il
        const int n   = row0 + rr;            // global sorted-tuple index
        float acc;
        if (ORD == 3) {
            int nn = n, aa = 0;
            while (true) { int ca = (9 - aa) * (10 - aa) / 2; if (nn < ca) break; nn -= ca; ++aa; }
            int bb = aa;
            while (true) { int cb = 9 - bb; if (nn < cb) break; nn -= cb; ++bb; }
            const int jj = bb + nn;
            int L[6];
            L[0] = (aa * 9 + bb) * 9 + jj; L[1] = (aa * 9 + jj) * 9 + bb;
            L[2] = (bb * 9 + aa) * 9 + jj; L[3] = (bb * 9 + jj) * 9 + aa;
            L[4] = (jj * 9 + aa) * 9 + bb; L[5] = (jj * 9 + bb) * 9 + aa;
            acc = 0.f;
            for (int m = 0; m < 6; ++m) {
                bool dup = false;
                for (int q = 0; q < m; ++q) dup = dup || (L[q] == L[m]);
                if (!dup) acc += u[L[m] * mi + rem];
            }
        } else if (ORD == 2) {
            int nn = n, aa = 0;
            while (true) { int cb = 9 - aa; if (nn < cb) break; nn -= cb; ++aa; }
            const int bb = aa + nn;
            acc = u[(aa * 9 + bb) * mi + rem];
            if (aa != bb) acc += u[(bb * 9 + aa) * mi + rem];
        } else {
            acc = u[n * mi + rem];
        }
        sU[f] = acc;
    }
    for (int idx = tid; idx < MUL * 32; idx += 128) {
        const int k = idx >> 5, cc = idx & 31;
        sW[idx] = W[(s * MUL + k) * C_CH + c0 + cc];
    }
    __syncthreads();

    const int nel = rows * IRD;
    for (int f = tid; f < nel; f += 128) {
        const int rr = f / IRD;
        const int il = f - rr * IRD;
        float uv[MUL];
#pragma unroll
        for (int k = 0; k < MUL; ++k) uv[k] = sU[(rr * MUL + k) * IRD + il];
        const int m = MOFF + row0 + rr;
        const int i = IOFF + il;
        const int off = (i < 8) ? (m * 8 + i) : (MAIN_F + m);
        for (int cc = 0; cc < 32; ++cc) {   // per cc: 64 lanes -> consecutive offs, coalesced
            float acc = 0.f;
#pragma unroll
            for (int k = 0; k < MUL; ++k) acc += uv[k] * sW[k * 32 + cc];
            Cg[(size_t)(s * C_CH + c0 + cc) * PAGE2 + off] = acc;
        }
    }
}

__global__ __launch_bounds__(128) void prep_kernel(Params p, const int* __restrict__ index,
                                                   int* __restrict__ counts,
                                                   int* __restrict__ lists,
                                                   float* __restrict__ Cg) {
    const int bx = blockIdx.x;
    if (bx == N_SPEC * 120) {   // --- bucket block ---
        __shared__ int sc[N_SPEC];
        const int tid = threadIdx.x;
        if (tid < N_SPEC) sc[tid] = 0;
        __syncthreads();
        for (int n = tid; n < N_NODES; n += 128) {
            int s = index[n];
            int pos = atomicAdd(&sc[s], 1);
            lists[s * N_NODES + pos] = n;
        }
        __syncthreads();
        if (tid < N_SPEC) counts[tid] = sc[tid];
        return;
    }
    __shared__ float sU[1560];   // max chunk: 24 rows * 13 * 5
    __shared__ float sW[13 * 32];
    const int s   = bx / 120;
    const int rem = bx % 120;
    const int t   = rem / 4;
    const int c0  = (rem % 4) * 32;

    if (t < 7) {
        int rel = t, row0 = rel * 24, rows = (rel == 6) ? 21 : 24;
        coefRegion3<3, 10, 1, 0, 0>(p.U3[0], p.W3[0], s, row0, rows, c0, Cg, sU, sW);
    } else if (t < 14) {
        int rel = t - 7, row0 = rel * 24, rows = (rel == 6) ? 21 : 24;
        coefRegion3<3, 11, 3, 1, 0>(p.U3[1], p.W3[1], s, row0, rows, c0, Cg, sU, sW);
    } else if (t < 21) {
        int rel = t - 14, row0 = rel * 24, rows = (rel == 6) ? 21 : 24;
        coefRegion3<3, 13, 5, 4, 0>(p.U3[2], p.W3[2], s, row0, rows, c0, Cg, sU, sW);
    } else if (t < 23) {
        int rel = t - 21, row0 = rel * 24, rows = (rel == 1) ? 21 : 24;
        coefRegion3<2, 3, 1, 0, 165>(p.U2[0], p.W2[0], s, row0, rows, c0, Cg, sU, sW);
    } else if (t < 25) {
        int rel = t - 23, row0 = rel * 24, rows = (rel == 1) ? 21 : 24;
        coefRegion3<2, 2, 3, 1, 165>(p.U2[1], p.W2[1], s, row0, rows, c0, Cg, sU, sW);
    } else if (t < 27) {
        int rel = t - 25, row0 = rel * 24, rows = (rel == 1) ? 21 : 24;
        coefRegion3<2, 3, 5, 4, 165>(p.U2[2], p.W2[2], s, row0, rows, c0, Cg, sU, sW);
    } else if (t == 27) {
        coefRegion3<1, 1, 1, 0, 210>(p.U1[0], p.W1[0], s, 0, 9, c0, Cg, sU, sW);
    } else if (t == 28) {
        coefRegion3<1, 1, 3, 1, 210>(p.U1[1], p.W1[1], s, 0, 9, c0, Cg, sU, sW);
    } else {
        // ROUND-6 BUG WAS HERE: MUL must be 1 (was 5) for U1_2e [9][1][5]
        coefRegion3<1, 1, 5, 4, 210>(p.U1[2], p.W1[2], s, 0, 9, c0, Cg, sU, sW);
    }
}

// ---------------------------------------------------------------------------
// Kernel 2: evaluation. One block per (species, channel), 64 threads, 4 nodes
// per thread. The monomial stream is fully static: bodyA<A> templates the
// outer index so every x[][] index and every LDS offset is compile-time ->
// no selx cndmask chains, and the compiler can batch ds_reads deeply
// (static offsets, m97-style clustering). sched_barrier(0) between bodies
// bounds hoisting scope (round-3 spill rail); __launch_bounds__(64,1) leaves
// VGPR uncapped (only ~5 waves/CU exist at this grid anyway).
// ---------------------------------------------------------------------------
template <int A>
__device__ inline void bodyA(const float4* __restrict__ Cv, const float* __restrict__ Ct,
                             const float (&x)[4][9],
                             float4 (&oA)[4], float4 (&oB)[4], float (&o8)[4],
                             int& m2, int& m3) {
    float xa[4];
#pragma unroll
    for (int u = 0; u < 4; ++u) xa[u] = x[u][A];
    {   // S1 monomial m = 210+A
        const float4 ca = Cv[(210 + A) * 2], cb = Cv[(210 + A) * 2 + 1];
        const float  c8 = Ct[210 + A];
#pragma unroll
        for (int u = 0; u < 4; ++u) {
            oA[u] += ca * xa[u]; oB[u] += cb * xa[u]; o8[u] += c8 * xa[u];
        }
    }
#pragma unroll
    for (int b = A; b < 9; ++b) {
        float xb[4];
#pragma unroll
        for (int u = 0; u < 4; ++u) xb[u] = x[u][b] * xa[u];
        {   // S2 monomial
            const float4 ca = Cv[(165 + m2) * 2], cb = Cv[(165 + m2) * 2 + 1];
            const float  c8 = Ct[165 + m2];
#pragma unroll
            for (int u = 0; u < 4; ++u) {
                oA[u] += ca * xb[u]; oB[u] += cb * xb[u]; o8[u] += c8 * xb[u];
            }
            ++m2;
        }
#pragma unroll
        for (int j = b; j < 9; ++j) {   // S3 monomials
            const float4 ca = Cv[m3 * 2], cb = Cv[m3 * 2 + 1];
            const float  c8 = Ct[m3];
#pragma unroll
            for (int u = 0; u < 4; ++u) {
                const float mn = x[u][j] * xb[u];
                oA[u] += ca * mn; oB[u] += cb * mn; o8[u] += c8 * mn;
            }
            ++m3;
        }
    }
}

__global__ __launch_bounds__(64, 1) void sc_eval_kernel(const float* __restrict__ nf,
                                                        const int* __restrict__ counts,
                                                        const int* __restrict__ lists,
                                                        const float* __restrict__ Cg,
                                                        float* __restrict__ out) {
    __shared__ __align__(16) float sP[PAGE2];
    const int s = blockIdx.x / C_CH;   // 128 consecutive blocks share a species
    const int c = blockIdx.x % C_CH;
    const float* __restrict__ Cp = Cg + (size_t)(s * C_CH + c) * PAGE2;

    {   // flat coalesced 8 KB stage: 64 threads x 8 float4
        const float4* g = (const float4*)Cp;
        float4* l = (float4*)sP;
#pragma unroll
        for (int q = 0; q < 8; ++q) l[threadIdx.x + 64 * q] = g[threadIdx.x + 64 * q];
    }
    __syncthreads();

    const int cnt = counts[s];
    const float4* __restrict__ Cv = (const float4*)sP;
    const float*  __restrict__ Ct = sP + MAIN_F;

    for (int base = 0; base < cnt; base += 256) {
        int mm[4];
        float x[4][9];
#pragma unroll
        for (int u = 0; u < 4; ++u) {
            const int i = base + threadIdx.x + 64 * u;
            mm[u] = (i < cnt) ? lists[s * N_NODES + i] : -1;
            const float* xp = nf + ((long)(mm[u] < 0 ? 0 : mm[u]) * C_CH + c) * 9;
#pragma unroll
            for (int j = 0; j < 9; ++j) x[u][j] = xp[j];
        }

        float4 oA[4], oB[4];
        float  o8[4];
#pragma unroll
        for (int u = 0; u < 4; ++u) {
            oA[u] = {0, 0, 0, 0}; oB[u] = {0, 0, 0, 0}; o8[u] = 0.f;
        }

        int m2 = 0, m3 = 0;
        bodyA<0>(Cv, Ct, x, oA, oB, o8, m2, m3); __builtin_amdgcn_sched_barrier(0);
        bodyA<1>(Cv, Ct, x, oA, oB, o8, m2, m3); __builtin_amdgcn_sched_barrier(0);
        bodyA<2>(Cv, Ct, x, oA, oB, o8, m2, m3); __builtin_amdgcn_sched_barrier(0);
        bodyA<3>(Cv, Ct, x, oA, oB, o8, m2, m3); __builtin_amdgcn_sched_barrier(0);
        bodyA<4>(Cv, Ct, x, oA, oB, o8, m2, m3); __builtin_amdgcn_sched_barrier(0);
        bodyA<5>(Cv, Ct, x, oA, oB, o8, m2, m3); __builtin_amdgcn_sched_barrier(0);
        bodyA<6>(Cv, Ct, x, oA, oB, o8, m2, m3); __builtin_amdgcn_sched_barrier(0);
        bodyA<7>(Cv, Ct, x, oA, oB, o8, m2, m3); __builtin_amdgcn_sched_barrier(0);
        bodyA<8>(Cv, Ct, x, oA, oB, o8, m2, m3);

#pragma unroll
        for (int u = 0; u < 4; ++u) {
            if (mm[u] >= 0) {
                float* op = out + ((long)mm[u] * C_CH + c) * 9;
                op[0] = oA[u].x; op[1] = oA[u].y; op[2] = oA[u].z; op[3] = oA[u].w;
                op[4] = oB[u].x; op[5] = oB[u].y; op[6] = oB[u].z; op[7] = oB[u].w;
                op[8] = o8[u];
            }
        }
    }
}

// ---------------------------------------------------------------------------
// Fallback path (round-0 verified kernels) in case ws_size is too small.
// ---------------------------------------------------------------------------
__global__ __launch_bounds__(1024) void bucket_kernel(const int* __restrict__ index,
                                                      int* __restrict__ counts,
                                                      int* __restrict__ lists) {
    __shared__ int sc[N_SPEC];
    const int tid = threadIdx.x;
    if (tid < N_SPEC) sc[tid] = 0;
    __syncthreads();
    for (int n = tid; n < N_NODES; n += blockDim.x) {
        int s = index[n];
        int pos = atomicAdd(&sc[s], 1);
        lists[s * N_NODES + pos] = n;
    }
    __syncthreads();
    if (tid < N_SPEC) counts[tid] = sc[tid];
}

template <int NAB, int MUL, int IRD, int IOFF>
__device__ inline void buildC(const float* __restrict__ u, const float* __restrict__ w,
                              int s, int c, float* __restrict__ sMain, float* __restrict__ sB) {
    const int tid = threadIdx.x;
    const float* wp = w + (s * MUL) * C_CH + c;
    for (int e = tid; e < NAB * IRD; e += 128) {
        int abj = e / IRD;
        int il  = e - abj * IRD;
        const float* up = u + (abj * MUL) * IRD + il;
        float acc = 0.f;
#pragma unroll
        for (int k = 0; k < MUL; ++k)
            acc += up[k * IRD] * wp[k * C_CH];
        int i = IOFF + il;
        if (i < 8) sMain[abj * 8 + i] = acc;
        else       sB[abj] = acc;
    }
}

__device__ inline float selx(const float x[9], int a) {
    float r = x[0];
    r = (a == 1) ? x[1] : r; r = (a == 2) ? x[2] : r; r = (a == 3) ? x[3] : r;
    r = (a == 4) ? x[4] : r; r = (a == 5) ? x[5] : r; r = (a == 6) ? x[6] : r;
    r = (a == 7) ? x[7] : r; r = (a == 8) ? x[8] : r;
    return r;
}

__global__ __launch_bounds__(128) void sc_kernel(const float* __restrict__ nf,
                                                 const int* __restrict__ counts,
                                                 const int* __restrict__ lists,
                                                 Params p,
                                                 float* __restrict__ out) {
    __shared__ __align__(16) float sC3[729 * 8];
    __shared__ float sC3b[729];
    __shared__ __align__(16) float sC2[81 * 8];
    __shared__ float sC2b[81];
    __shared__ __align__(16) float sC1[9 * 8];
    __shared__ float sC1b[9];

    const int s = blockIdx.x % N_SPEC;
    const int c = blockIdx.x / N_SPEC;
    const int tid = threadIdx.x;

    buildC<729, 10, 1, 0>(p.U3[0], p.W3[0], s, c, sC3, sC3b);
    buildC<729, 11, 3, 1>(p.U3[1], p.W3[1], s, c, sC3, sC3b);
    buildC<729, 13, 5, 4>(p.U3[2], p.W3[2], s, c, sC3, sC3b);
    buildC<81, 3, 1, 0>(p.U2[0], p.W2[0], s, c, sC2, sC2b);
    buildC<81, 2, 3, 1>(p.U2[1], p.W2[1], s, c, sC2, sC2b);
    buildC<81, 3, 5, 4>(p.U2[2], p.W2[2], s, c, sC2, sC2b);
    buildC<9, 1, 1, 0>(p.U1[0], p.W1[0], s, c, sC1, sC1b);
    buildC<9, 1, 3, 1>(p.U1[1], p.W1[1], s, c, sC1, sC1b);
    buildC<9, 1, 5, 4>(p.U1[2], p.W1[2], s, c, sC1, sC1b);
    __syncthreads();

    const int cnt = counts[s];
    const float4* C3v = (const float4*)sC3;
    const float4* C2v = (const float4*)sC2;
    const float4* C1v = (const float4*)sC1;

    for (int base = 0; base < cnt; base += 256) {
        const int i0 = base + tid;
        const int i1 = base + 128 + tid;
        const int m0 = (i0 < cnt) ? lists[s * N_NODES + i0] : -1;
        const int m1 = (i1 < cnt) ? lists[s * N_NODES + i1] : -1;

        const float* x0p = nf + ((long)(m0 < 0 ? 0 : m0) * C_CH + c) * 9;
        const float* x1p = nf + ((long)(m1 < 0 ? 0 : m1) * C_CH + c) * 9;
        float x0[9], x1[9];
#pragma unroll
        for (int j = 0; j < 9; ++j) { x0[j] = x0p[j]; x1[j] = x1p[j]; }

        float4 o0a = {0, 0, 0, 0}, o0b = {0, 0, 0, 0};
        float4 o1a = {0, 0, 0, 0}, o1b = {0, 0, 0, 0};
        float o08 = 0.f, o18 = 0.f;

#pragma unroll 1
        for (int a = 0; a < 9; ++a) {
            const float xa0 = selx(x0, a);
            const float xa1 = selx(x1, a);
            const float4 c1a = C1v[a * 2], c1b = C1v[a * 2 + 1];
            const float  c18 = sC1b[a];
            float4 q0a = c1a, q0b = c1b; float q08 = c18;
            float4 q1a = c1a, q1b = c1b; float q18 = c18;
#pragma unroll
            for (int b = 0; b < 9; ++b) {
                const int ab = a * 9 + b;
                const float4 c2a = C2v[ab * 2], c2b = C2v[ab * 2 + 1];
                const float  c28 = sC2b[ab];
                float4 t0a = c2a, t0b = c2b; float t08 = c28;
                float4 t1a = c2a, t1b = c2b; float t18 = c28;
#pragma unroll
                for (int j = 0; j < 9; ++j) {
                    const int abj = ab * 9 + j;
                    const float4 ca = C3v[abj * 2];
                    const float4 cb = C3v[abj * 2 + 1];
                    const float  c8 = sC3b[abj];
                    t0a += ca * x0[j]; t0b += cb * x0[j]; t08 += c8 * x0[j];
                    t1a += ca * x1[j]; t1b += cb * x1[j]; t18 += c8 * x1[j];
                }
                q0a += t0a * x0[b]; q0b += t0b * x0[b]; q08 += t08 * x0[b];
                q1a += t1a * x1[b]; q1b += t1b * x1[b]; q18 += t18 * x1[b];
            }
            o0a += q0a * xa0; o0b += q0b * xa0; o08 += q08 * xa0;
            o1a += q1a * xa1; o1b += q1b * xa1; o18 += q18 * xa1;
        }

        if (m0 >= 0) {
            float* op = out + ((long)m0 * C_CH + c) * 9;
            op[0] = o0a.x; op[1] = o0a.y; op[2] = o0a.z; op[3] = o0a.w;
            op[4] = o0b.x; op[5] = o0b.y; op[6] = o0b.z; op[7] = o0b.w;
            op[8] = o08;
        }
        if (m1 >= 0) {
            float* op = out + ((long)m1 * C_CH + c) * 9;
            op[0] = o1a.x; op[1] = o1a.y; op[2] = o1a.z; op[3] = o1a.w;
            op[4] = o1b.x; op[5] = o1b.y; op[6] = o1b.z; op[7] = o1b.w;
            op[8] = o18;
        }
    }
}

// ---------------------------------------------------------------------------
extern "C" void kernel_launch(void* const* d_in, const int* in_sizes, int n_in,
                              void* d_out, int out_size, void* d_ws, size_t ws_size,
                              hipStream_t stream) {
    const float* nf   = (const float*)d_in[0];
    const int* index  = (const int*)d_in[1];

    Params p;
    p.U3[0] = (const float*)d_in[2];  p.W3[0] = (const float*)d_in[3];
    p.U3[1] = (const float*)d_in[4];  p.W3[1] = (const float*)d_in[5];
    p.U3[2] = (const float*)d_in[6];  p.W3[2] = (const float*)d_in[7];
    p.U2[0] = (const float*)d_in[8];  p.W2[0] = (const float*)d_in[9];
    p.U2[1] = (const float*)d_in[10]; p.W2[1] = (const float*)d_in[11];
    p.U2[2] = (const float*)d_in[12]; p.W2[2] = (const float*)d_in[13];
    p.U1[0] = (const float*)d_in[14]; p.W1[0] = (const float*)d_in[15];
    p.U1[1] = (const float*)d_in[16]; p.W1[1] = (const float*)d_in[17];
    p.U1[2] = (const float*)d_in[18]; p.W1[2] = (const float*)d_in[19];

    int* counts = (int*)d_ws;        // 16 ints
    int* lists  = (int*)d_ws + 16;   // 10 * 2048 ints, ends at 81,984 B

    if (ws_size >= (size_t)CG_OFF_B + CG_BYTES) {
        float* Cg = (float*)((char*)d_ws + CG_OFF_B);
        prep_kernel<<<N_SPEC * 120 + 1, 128, 0, stream>>>(p, index, counts, lists, Cg);
        sc_eval_kernel<<<N_SPEC * C_CH, 64, 0, stream>>>(nf, counts, lists, Cg,
                                                         (float*)d_out);
    } else {
        bucket_kernel<<<1, 1024, 0, stream>>>(index, counts, lists);
        sc_kernel<<<N_SPEC * C_CH, 128, 0, stream>>>(nf, counts, lists, p,
                                                     (float*)d_out);
    }
}

// Round 8
// 905.556 us; speedup vs baseline: 1.4384x; 1.4384x over previous
//
#include <hip/hip_runtime.h>

#define N_NODES 2048
#define C_CH    128
#define N_SPEC  10

// --- symmetric-reduced coefficient page per (species, channel) ---------------
// Global layout (unchanged, prep-verified): main[219][8] | tail[219], pad 2048.
// Monomial order: m=0..164 sorted triples a<=b<=j (lex), 165..209 sorted pairs
// a<=b (lex), 210..218 singles a.
#define PAGE2   2048
#define MAIN_F  1752          // 219*8

#define CG_OFF_B  (256 * 1024)
#define CG_BYTES  ((size_t)N_SPEC * C_CH * PAGE2 * 4)

struct Params {
    const float* U3[3]; const float* W3[3];
    const float* U2[3]; const float* W2[3];
    const float* U1[3]; const float* W1[3];
};

// ---------------------------------------------------------------------------
// Kernel 1 (fused prep) — verified round 7 (with the MUL=1 fix).
// ---------------------------------------------------------------------------
template <int ORD, int MUL, int IRD, int IOFF, int MOFF>
__device__ inline void coefRegion3(const float* __restrict__ u,
                                   const float* __restrict__ W,
                                   int s, int row0, int rows, int c0,
                                   float* __restrict__ Cg,
                                   float* __restrict__ sU, float* __restrict__ sW) {
    const int tid = threadIdx.x;
    const int mi  = MUL * IRD;
    const int nfl = rows * mi;
    for (int f = tid; f < nfl; f += 128) {
        const int rr  = f / mi;
        const int rem = f - rr * mi;
        const int n   = row0 + rr;
        float acc;
        if (ORD == 3) {
            int nn = n, aa = 0;
            while (true) { int ca = (9 - aa) * (10 - aa) / 2; if (nn < ca) break; nn -= ca; ++aa; }
            int bb = aa;
            while (true) { int cb = 9 - bb; if (nn < cb) break; nn -= cb; ++bb; }
            const int jj = bb + nn;
            int L[6];
            L[0] = (aa * 9 + bb) * 9 + jj; L[1] = (aa * 9 + jj) * 9 + bb;
            L[2] = (bb * 9 + aa) * 9 + jj; L[3] = (bb * 9 + jj) * 9 + aa;
            L[4] = (jj * 9 + aa) * 9 + bb; L[5] = (jj * 9 + bb) * 9 + aa;
            acc = 0.f;
            for (int m = 0; m < 6; ++m) {
                bool dup = false;
                for (int q = 0; q < m; ++q) dup = dup || (L[q] == L[m]);
                if (!dup) acc += u[L[m] * mi + rem];
            }
        } else if (ORD == 2) {
            int nn = n, aa = 0;
            while (true) { int cb = 9 - aa; if (nn < cb) break; nn -= cb; ++aa; }
            const int bb = aa + nn;
            acc = u[(aa * 9 + bb) * mi + rem];
            if (aa != bb) acc += u[(bb * 9 + aa) * mi + rem];
        } else {
            acc = u[n * mi + rem];
        }
        sU[f] = acc;
    }
    for (int idx = tid; idx < MUL * 32; idx += 128) {
        const int k = idx >> 5, cc = idx & 31;
        sW[idx] = W[(s * MUL + k) * C_CH + c0 + cc];
    }
    __syncthreads();

    const int nel = rows * IRD;
    for (int f = tid; f < nel; f += 128) {
        const int rr = f / IRD;
        const int il = f - rr * IRD;
        float uv[MUL];
#pragma unroll
        for (int k = 0; k < MUL; ++k) uv[k] = sU[(rr * MUL + k) * IRD + il];
        const int m = MOFF + row0 + rr;
        const int i = IOFF + il;
        const int off = (i < 8) ? (m * 8 + i) : (MAIN_F + m);
        for (int cc = 0; cc < 32; ++cc) {
            float acc = 0.f;
#pragma unroll
            for (int k = 0; k < MUL; ++k) acc += uv[k] * sW[k * 32 + cc];
            Cg[(size_t)(s * C_CH + c0 + cc) * PAGE2 + off] = acc;
        }
    }
}

__global__ __launch_bounds__(128) void prep_kernel(Params p, const int* __restrict__ index,
                                                   int* __restrict__ counts,
                                                   int* __restrict__ lists,
                                                   float* __restrict__ Cg) {
    const int bx = blockIdx.x;
    if (bx == N_SPEC * 120) {   // --- bucket block ---
        __shared__ int sc[N_SPEC];
        const int tid = threadIdx.x;
        if (tid < N_SPEC) sc[tid] = 0;
        __syncthreads();
        for (int n = tid; n < N_NODES; n += 128) {
            int s = index[n];
            int pos = atomicAdd(&sc[s], 1);
            lists[s * N_NODES + pos] = n;
        }
        __syncthreads();
        if (tid < N_SPEC) counts[tid] = sc[tid];
        return;
    }
    __shared__ float sU[1560];
    __shared__ float sW[13 * 32];
    const int s   = bx / 120;
    const int rem = bx % 120;
    const int t   = rem / 4;
    const int c0  = (rem % 4) * 32;

    if (t < 7) {
        int rel = t, row0 = rel * 24, rows = (rel == 6) ? 21 : 24;
        coefRegion3<3, 10, 1, 0, 0>(p.U3[0], p.W3[0], s, row0, rows, c0, Cg, sU, sW);
    } else if (t < 14) {
        int rel = t - 7, row0 = rel * 24, rows = (rel == 6) ? 21 : 24;
        coefRegion3<3, 11, 3, 1, 0>(p.U3[1], p.W3[1], s, row0, rows, c0, Cg, sU, sW);
    } else if (t < 21) {
        int rel = t - 14, row0 = rel * 24, rows = (rel == 6) ? 21 : 24;
        coefRegion3<3, 13, 5, 4, 0>(p.U3[2], p.W3[2], s, row0, rows, c0, Cg, sU, sW);
    } else if (t < 23) {
        int rel = t - 21, row0 = rel * 24, rows = (rel == 1) ? 21 : 24;
        coefRegion3<2, 3, 1, 0, 165>(p.U2[0], p.W2[0], s, row0, rows, c0, Cg, sU, sW);
    } else if (t < 25) {
        int rel = t - 23, row0 = rel * 24, rows = (rel == 1) ? 21 : 24;
        coefRegion3<2, 2, 3, 1, 165>(p.U2[1], p.W2[1], s, row0, rows, c0, Cg, sU, sW);
    } else if (t < 27) {
        int rel = t - 25, row0 = rel * 24, rows = (rel == 1) ? 21 : 24;
        coefRegion3<2, 3, 5, 4, 165>(p.U2[2], p.W2[2], s, row0, rows, c0, Cg, sU, sW);
    } else if (t == 27) {
        coefRegion3<1, 1, 1, 0, 210>(p.U1[0], p.W1[0], s, 0, 9, c0, Cg, sU, sW);
    } else if (t == 28) {
        coefRegion3<1, 1, 3, 1, 210>(p.U1[1], p.W1[1], s, 0, 9, c0, Cg, sU, sW);
    } else {
        coefRegion3<1, 1, 5, 4, 210>(p.U1[2], p.W1[2], s, 0, 9, c0, Cg, sU, sW);
    }
}

// ---------------------------------------------------------------------------
// Kernel 2: evaluation, "split-plane uniform" scheme.
// LDS page restaged as [219][16] floats: {c0..3, c8, -, -, -, c4..7, c8, -,-,-}.
// 128 threads = 2 waves; BOTH waves process the same 256 nodes (4/thread);
// wave w reads its half-plane at uniform float offset w*8 -> ONE code path.
// Per monomial per wave: 1 ds_read_b128 + 1 ds_read_b32 + 4 muls + 20 FMA.
// Static a,b,j via templates (no selx cndmask chains); sched_barrier(0) after
// EVERY b-body (<=10 monomials) bounds the hoisting window (round-7 spill rail
// was 55-monomial windows -> 256 VGPR + 1.6 GB scratch).
// Wave0 writes out[0..3]+out[8]; wave1 writes out[4..7].
// ---------------------------------------------------------------------------
__device__ constexpr int pairIdx(int a, int b) {   // index among sorted pairs
    int s = 0;
    for (int t = 0; t < a; ++t) s += 9 - t;
    return s + (b - a);
}
__device__ constexpr int triBase(int a, int b) {   // first triple (a,b,*)
    int s = 0;
    for (int t = 0; t < a; ++t) s += (9 - t) * (10 - t) / 2;
    for (int t = a; t < b; ++t) s += 9 - t;
    return s;
}

template <int A, int B>
__device__ __forceinline__ void bodyB(const float* __restrict__ sP, int woff,
                                      const float (&x)[4][9],
                                      float4 (&oM)[4], float (&o8)[4]) {
    float xab[4];
#pragma unroll
    for (int u = 0; u < 4; ++u) xab[u] = x[u][A] * x[u][B];
    {   // S2 monomial
        constexpr int m = 165 + pairIdx(A, B);
        const float4 cm = *(const float4*)&sP[m * 16 + woff];
        const float  c8 = sP[m * 16 + 4 + woff];
#pragma unroll
        for (int u = 0; u < 4; ++u) { oM[u] += cm * xab[u]; o8[u] += c8 * xab[u]; }
    }
#pragma unroll
    for (int j = B; j < 9; ++j) {   // S3 monomials (j static after unroll)
        const int m = triBase(A, B) + (j - B);
        const float4 cm = *(const float4*)&sP[m * 16 + woff];
        const float  c8 = sP[m * 16 + 4 + woff];
#pragma unroll
        for (int u = 0; u < 4; ++u) {
            const float mn = xab[u] * x[u][j];
            oM[u] += cm * mn; o8[u] += c8 * mn;
        }
    }
}

template <int A, int B>
struct BChain {
    static __device__ __forceinline__ void run(const float* __restrict__ sP, int woff,
                                               const float (&x)[4][9],
                                               float4 (&oM)[4], float (&o8)[4]) {
        bodyB<A, B>(sP, woff, x, oM, o8);
        __builtin_amdgcn_sched_barrier(0);
        BChain<A, B + 1>::run(sP, woff, x, oM, o8);
    }
};
template <int A>
struct BChain<A, 9> {
    static __device__ __forceinline__ void run(const float*, int, const float (&)[4][9],
                                               float4 (&)[4], float (&)[4]) {}
};

template <int A>
__device__ __forceinline__ void bodyA(const float* __restrict__ sP, int woff,
                                      const float (&x)[4][9],
                                      float4 (&oM)[4], float (&o8)[4]) {
    {   // S1 monomial m = 210+A
        constexpr int m = 210 + A;
        const float4 cm = *(const float4*)&sP[m * 16 + woff];
        const float  c8 = sP[m * 16 + 4 + woff];
#pragma unroll
        for (int u = 0; u < 4; ++u) {
            const float xa = x[u][A];
            oM[u] += cm * xa; o8[u] += c8 * xa;
        }
    }
    __builtin_amdgcn_sched_barrier(0);
    BChain<A, A>::run(sP, woff, x, oM, o8);
}

__global__ __launch_bounds__(128, 1) void sc_eval_kernel(const float* __restrict__ nf,
                                                         const int* __restrict__ counts,
                                                         const int* __restrict__ lists,
                                                         const float* __restrict__ Cg,
                                                         float* __restrict__ out) {
    __shared__ __align__(16) float sP[219 * 16];
    const int s = blockIdx.x / C_CH;
    const int c = blockIdx.x % C_CH;
    const float* __restrict__ Cp = Cg + (size_t)(s * C_CH + c) * PAGE2;

    {   // restage 8KB page -> [219][16] split-plane layout
        const float4* Gv = (const float4*)Cp;
        for (int m = threadIdx.x; m < 219; m += 128) {
            const float4 v1 = Gv[m * 2];
            const float4 v2 = Gv[m * 2 + 1];
            const float  t  = Cp[MAIN_F + m];
            float4* L = (float4*)&sP[m * 16];
            L[0] = v1;                 // floats 0..3   = c0..c3
            L[2] = v2;                 // floats 8..11  = c4..c7
            sP[m * 16 + 4]  = t;       // c8 (wave0 plane)
            sP[m * 16 + 12] = t;       // c8 dup (wave1 plane)
        }
    }
    __syncthreads();

    const int cnt  = counts[s];
    const int wid  = threadIdx.x >> 6;       // wave id: 0 or 1 (uniform)
    const int lane = threadIdx.x & 63;
    const int woff = wid * 8;                // float offset into half-plane

    for (int base = 0; base < cnt; base += 256) {
        int mm[4];
        float x[4][9];
#pragma unroll
        for (int u = 0; u < 4; ++u) {
            const int i = base + lane + 64 * u;          // both waves: same slots
            mm[u] = (i < cnt) ? lists[s * N_NODES + i] : -1;
            const float* xp = nf + ((long)(mm[u] < 0 ? 0 : mm[u]) * C_CH + c) * 9;
#pragma unroll
            for (int j = 0; j < 9; ++j) x[u][j] = xp[j];
        }

        float4 oM[4];
        float  o8[4];
#pragma unroll
        for (int u = 0; u < 4; ++u) { oM[u] = {0, 0, 0, 0}; o8[u] = 0.f; }

        bodyA<0>(sP, woff, x, oM, o8); __builtin_amdgcn_sched_barrier(0);
        bodyA<1>(sP, woff, x, oM, o8); __builtin_amdgcn_sched_barrier(0);
        bodyA<2>(sP, woff, x, oM, o8); __builtin_amdgcn_sched_barrier(0);
        bodyA<3>(sP, woff, x, oM, o8); __builtin_amdgcn_sched_barrier(0);
        bodyA<4>(sP, woff, x, oM, o8); __builtin_amdgcn_sched_barrier(0);
        bodyA<5>(sP, woff, x, oM, o8); __builtin_amdgcn_sched_barrier(0);
        bodyA<6>(sP, woff, x, oM, o8); __builtin_amdgcn_sched_barrier(0);
        bodyA<7>(sP, woff, x, oM, o8); __builtin_amdgcn_sched_barrier(0);
        bodyA<8>(sP, woff, x, oM, o8);

        if (wid == 0) {
#pragma unroll
            for (int u = 0; u < 4; ++u) {
                if (mm[u] >= 0) {
                    float* op = out + ((long)mm[u] * C_CH + c) * 9;
                    op[0] = oM[u].x; op[1] = oM[u].y; op[2] = oM[u].z; op[3] = oM[u].w;
                    op[8] = o8[u];
                }
            }
        } else {
#pragma unroll
            for (int u = 0; u < 4; ++u) {
                if (mm[u] >= 0) {
                    float* op = out + ((long)mm[u] * C_CH + c) * 9;
                    op[4] = oM[u].x; op[5] = oM[u].y; op[6] = oM[u].z; op[7] = oM[u].w;
                }
            }
        }
    }
}

// ---------------------------------------------------------------------------
// Fallback path (round-0 verified kernels) in case ws_size is too small.
// ---------------------------------------------------------------------------
__global__ __launch_bounds__(1024) void bucket_kernel(const int* __restrict__ index,
                                                      int* __restrict__ counts,
                                                      int* __restrict__ lists) {
    __shared__ int sc[N_SPEC];
    const int tid = threadIdx.x;
    if (tid < N_SPEC) sc[tid] = 0;
    __syncthreads();
    for (int n = tid; n < N_NODES; n += blockDim.x) {
        int s = index[n];
        int pos = atomicAdd(&sc[s], 1);
        lists[s * N_NODES + pos] = n;
    }
    __syncthreads();
    if (tid < N_SPEC) counts[tid] = sc[tid];
}

template <int NAB, int MUL, int IRD, int IOFF>
__device__ inline void buildC(const float* __restrict__ u, const float* __restrict__ w,
                              int s, int c, float* __restrict__ sMain, float* __restrict__ sB) {
    const int tid = threadIdx.x;
    const float* wp = w + (s * MUL) * C_CH + c;
    for (int e = tid; e < NAB * IRD; e += 128) {
        int abj = e / IRD;
        int il  = e - abj * IRD;
        const float* up = u + (abj * MUL) * IRD + il;
        float acc = 0.f;
#pragma unroll
        for (int k = 0; k < MUL; ++k)
            acc += up[k * IRD] * wp[k * C_CH];
        int i = IOFF + il;
        if (i < 8) sMain[abj * 8 + i] = acc;
        else       sB[abj] = acc;
    }
}

__device__ inline float selx(const float x[9], int a) {
    float r = x[0];
    r = (a == 1) ? x[1] : r; r = (a == 2) ? x[2] : r; r = (a == 3) ? x[3] : r;
    r = (a == 4) ? x[4] : r; r = (a == 5) ? x[5] : r; r = (a == 6) ? x[6] : r;
    r = (a == 7) ? x[7] : r; r = (a == 8) ? x[8] : r;
    return r;
}

__global__ __launch_bounds__(128) void sc_kernel(const float* __restrict__ nf,
                                                 const int* __restrict__ counts,
                                                 const int* __restrict__ lists,
                                                 Params p,
                                                 float* __restrict__ out) {
    __shared__ __align__(16) float sC3[729 * 8];
    __shared__ float sC3b[729];
    __shared__ __align__(16) float sC2[81 * 8];
    __shared__ float sC2b[81];
    __shared__ __align__(16) float sC1[9 * 8];
    __shared__ float sC1b[9];

    const int s = blockIdx.x % N_SPEC;
    const int c = blockIdx.x / N_SPEC;
    const int tid = threadIdx.x;

    buildC<729, 10, 1, 0>(p.U3[0], p.W3[0], s, c, sC3, sC3b);
    buildC<729, 11, 3, 1>(p.U3[1], p.W3[1], s, c, sC3, sC3b);
    buildC<729, 13, 5, 4>(p.U3[2], p.W3[2], s, c, sC3, sC3b);
    buildC<81, 3, 1, 0>(p.U2[0], p.W2[0], s, c, sC2, sC2b);
    buildC<81, 2, 3, 1>(p.U2[1], p.W2[1], s, c, sC2, sC2b);
    buildC<81, 3, 5, 4>(p.U2[2], p.W2[2], s, c, sC2, sC2b);
    buildC<9, 1, 1, 0>(p.U1[0], p.W1[0], s, c, sC1, sC1b);
    buildC<9, 1, 3, 1>(p.U1[1], p.W1[1], s, c, sC1, sC1b);
    buildC<9, 1, 5, 4>(p.U1[2], p.W1[2], s, c, sC1, sC1b);
    __syncthreads();

    const int cnt = counts[s];
    const float4* C3v = (const float4*)sC3;
    const float4* C2v = (const float4*)sC2;
    const float4* C1v = (const float4*)sC1;

    for (int base = 0; base < cnt; base += 256) {
        const int i0 = base + tid;
        const int i1 = base + 128 + tid;
        const int m0 = (i0 < cnt) ? lists[s * N_NODES + i0] : -1;
        const int m1 = (i1 < cnt) ? lists[s * N_NODES + i1] : -1;

        const float* x0p = nf + ((long)(m0 < 0 ? 0 : m0) * C_CH + c) * 9;
        const float* x1p = nf + ((long)(m1 < 0 ? 0 : m1) * C_CH + c) * 9;
        float x0[9], x1[9];
#pragma unroll
        for (int j = 0; j < 9; ++j) { x0[j] = x0p[j]; x1[j] = x1p[j]; }

        float4 o0a = {0, 0, 0, 0}, o0b = {0, 0, 0, 0};
        float4 o1a = {0, 0, 0, 0}, o1b = {0, 0, 0, 0};
        float o08 = 0.f, o18 = 0.f;

#pragma unroll 1
        for (int a = 0; a < 9; ++a) {
            const float xa0 = selx(x0, a);
            const float xa1 = selx(x1, a);
            const float4 c1a = C1v[a * 2], c1b = C1v[a * 2 + 1];
            const float  c18 = sC1b[a];
            float4 q0a = c1a, q0b = c1b; float q08 = c18;
            float4 q1a = c1a, q1b = c1b; float q18 = c18;
#pragma unroll
            for (int b = 0; b < 9; ++b) {
                const int ab = a * 9 + b;
                const float4 c2a = C2v[ab * 2], c2b = C2v[ab * 2 + 1];
                const float  c28 = sC2b[ab];
                float4 t0a = c2a, t0b = c2b; float t08 = c28;
                float4 t1a = c2a, t1b = c2b; float t18 = c28;
#pragma unroll
                for (int j = 0; j < 9; ++j) {
                    const int abj = ab * 9 + j;
                    const float4 ca = C3v[abj * 2];
                    const float4 cb = C3v[abj * 2 + 1];
                    const float  c8 = sC3b[abj];
                    t0a += ca * x0[j]; t0b += cb * x0[j]; t08 += c8 * x0[j];
                    t1a += ca * x1[j]; t1b += cb * x1[j]; t18 += c8 * x1[j];
                }
                q0a += t0a * x0[b]; q0b += t0b * x0[b]; q08 += t08 * x0[b];
                q1a += t1a * x1[b]; q1b += t1b * x1[b]; q18 += t18 * x1[b];
            }
            o0a += q0a * xa0; o0b += q0b * xa0; o08 += q08 * xa0;
            o1a += q1a * xa1; o1b += q1b * xa1; o18 += q18 * xa1;
        }

        if (m0 >= 0) {
            float* op = out + ((long)m0 * C_CH + c) * 9;
            op[0] = o0a.x; op[1] = o0a.y; op[2] = o0a.z; op[3] = o0a.w;
            op[4] = o0b.x; op[5] = o0b.y; op[6] = o0b.z; op[7] = o0b.w;
            op[8] = o08;
        }
        if (m1 >= 0) {
            float* op = out + ((long)m1 * C_CH + c) * 9;
            op[0] = o1a.x; op[1] = o1a.y; op[2] = o1a.z; op[3] = o1a.w;
            op[4] = o1b.x; op[5] = o1b.y; op[6] = o1b.z; op[7] = o1b.w;
            op[8] = o18;
        }
    }
}

// ---------------------------------------------------------------------------
extern "C" void kernel_launch(void* const* d_in, const int* in_sizes, int n_in,
                              void* d_out, int out_size, void* d_ws, size_t ws_size,
                              hipStream_t stream) {
    const float* nf   = (const float*)d_in[0];
    const int* index  = (const int*)d_in[1];

    Params p;
    p.U3[0] = (const float*)d_in[2];  p.W3[0] = (const float*)d_in[3];
    p.U3[1] = (const float*)d_in[4];  p.W3[1] = (const float*)d_in[5];
    p.U3[2] = (const float*)d_in[6];  p.W3[2] = (const float*)d_in[7];
    p.U2[0] = (const float*)d_in[8];  p.W2[0] = (const float*)d_in[9];
    p.U2[1] = (const float*)d_in[10]; p.W2[1] = (const float*)d_in[11];
    p.U2[2] = (const float*)d_in[12]; p.W2[2] = (const float*)d_in[13];
    p.U1[0] = (const float*)d_in[14]; p.W1[0] = (const float*)d_in[15];
    p.U1[1] = (const float*)d_in[16]; p.W1[1] = (const float*)d_in[17];
    p.U1[2] = (const float*)d_in[18]; p.W1[2] = (const float*)d_in[19];

    int* counts = (int*)d_ws;        // 16 ints
    int* lists  = (int*)d_ws + 16;   // 10 * 2048 ints, ends at 81,984 B

    if (ws_size >= (size_t)CG_OFF_B + CG_BYTES) {
        float* Cg = (float*)((char*)d_ws + CG_OFF_B);
        prep_kernel<<<N_SPEC * 120 + 1, 128, 0, stream>>>(p, index, counts, lists, Cg);
        sc_eval_kernel<<<N_SPEC * C_CH, 128, 0, stream>>>(nf, counts, lists, Cg,
                                                          (float*)d_out);
    } else {
        bucket_kernel<<<1, 1024, 0, stream>>>(index, counts, lists);
        sc_kernel<<<N_SPEC * C_CH, 128, 0, stream>>>(nf, counts, lists, p,
                                                     (float*)d_out);
    }
}

// Round 9
// 898.568 us; speedup vs baseline: 1.4496x; 1.0078x over previous
//
#include <hip/hip_runtime.h>

#define N_NODES 2048
#define C_CH    128
#define N_SPEC  10

// --- symmetric-reduced coefficient page per (species, channel) ---------------
// Global layout (unchanged, prep-verified): main[219][8] | tail[219], pad 2048.
// Monomial order: m=0..164 sorted triples a<=b<=j (lex), 165..209 sorted pairs
// a<=b (lex), 210..218 singles a.
#define PAGE2   2048
#define MAIN_F  1752          // 219*8

#define CG_OFF_B  (256 * 1024)
#define CG_BYTES  ((size_t)N_SPEC * C_CH * PAGE2 * 4)

struct Params {
    const float* U3[3]; const float* W3[3];
    const float* U2[3]; const float* W2[3];
    const float* U1[3]; const float* W1[3];
};

// ---------------------------------------------------------------------------
// Kernel 1 (fused prep) — verified round 7/8 (with the MUL=1 fix).
// ---------------------------------------------------------------------------
template <int ORD, int MUL, int IRD, int IOFF, int MOFF>
__device__ inline void coefRegion3(const float* __restrict__ u,
                                   const float* __restrict__ W,
                                   int s, int row0, int rows, int c0,
                                   float* __restrict__ Cg,
                                   float* __restrict__ sU, float* __restrict__ sW) {
    const int tid = threadIdx.x;
    const int mi  = MUL * IRD;
    const int nfl = rows * mi;
    for (int f = tid; f < nfl; f += 128) {
        const int rr  = f / mi;
        const int rem = f - rr * mi;
        const int n   = row0 + rr;
        float acc;
        if (ORD == 3) {
            int nn = n, aa = 0;
            while (true) { int ca = (9 - aa) * (10 - aa) / 2; if (nn < ca) break; nn -= ca; ++aa; }
            int bb = aa;
            while (true) { int cb = 9 - bb; if (nn < cb) break; nn -= cb; ++bb; }
            const int jj = bb + nn;
            int L[6];
            L[0] = (aa * 9 + bb) * 9 + jj; L[1] = (aa * 9 + jj) * 9 + bb;
            L[2] = (bb * 9 + aa) * 9 + jj; L[3] = (bb * 9 + jj) * 9 + aa;
            L[4] = (jj * 9 + aa) * 9 + bb; L[5] = (jj * 9 + bb) * 9 + aa;
            acc = 0.f;
            for (int m = 0; m < 6; ++m) {
                bool dup = false;
                for (int q = 0; q < m; ++q) dup = dup || (L[q] == L[m]);
                if (!dup) acc += u[L[m] * mi + rem];
            }
        } else if (ORD == 2) {
            int nn = n, aa = 0;
            while (true) { int cb = 9 - aa; if (nn < cb) break; nn -= cb; ++aa; }
            const int bb = aa + nn;
            acc = u[(aa * 9 + bb) * mi + rem];
            if (aa != bb) acc += u[(bb * 9 + aa) * mi + rem];
        } else {
            acc = u[n * mi + rem];
        }
        sU[f] = acc;
    }
    for (int idx = tid; idx < MUL * 32; idx += 128) {
        const int k = idx >> 5, cc = idx & 31;
        sW[idx] = W[(s * MUL + k) * C_CH + c0 + cc];
    }
    __syncthreads();

    const int nel = rows * IRD;
    for (int f = tid; f < nel; f += 128) {
        const int rr = f / IRD;
        const int il = f - rr * IRD;
        float uv[MUL];
#pragma unroll
        for (int k = 0; k < MUL; ++k) uv[k] = sU[(rr * MUL + k) * IRD + il];
        const int m = MOFF + row0 + rr;
        const int i = IOFF + il;
        const int off = (i < 8) ? (m * 8 + i) : (MAIN_F + m);
        for (int cc = 0; cc < 32; ++cc) {
            float acc = 0.f;
#pragma unroll
            for (int k = 0; k < MUL; ++k) acc += uv[k] * sW[k * 32 + cc];
            Cg[(size_t)(s * C_CH + c0 + cc) * PAGE2 + off] = acc;
        }
    }
}

__global__ __launch_bounds__(128) void prep_kernel(Params p, const int* __restrict__ index,
                                                   int* __restrict__ counts,
                                                   int* __restrict__ lists,
                                                   float* __restrict__ Cg) {
    const int bx = blockIdx.x;
    if (bx == N_SPEC * 120) {   // --- bucket block ---
        __shared__ int sc[N_SPEC];
        const int tid = threadIdx.x;
        if (tid < N_SPEC) sc[tid] = 0;
        __syncthreads();
        for (int n = tid; n < N_NODES; n += 128) {
            int s = index[n];
            int pos = atomicAdd(&sc[s], 1);
            lists[s * N_NODES + pos] = n;
        }
        __syncthreads();
        if (tid < N_SPEC) counts[tid] = sc[tid];
        return;
    }
    __shared__ float sU[1560];
    __shared__ float sW[13 * 32];
    const int s   = bx / 120;
    const int rem = bx % 120;
    const int t   = rem / 4;
    const int c0  = (rem % 4) * 32;

    if (t < 7) {
        int rel = t, row0 = rel * 24, rows = (rel == 6) ? 21 : 24;
        coefRegion3<3, 10, 1, 0, 0>(p.U3[0], p.W3[0], s, row0, rows, c0, Cg, sU, sW);
    } else if (t < 14) {
        int rel = t - 7, row0 = rel * 24, rows = (rel == 6) ? 21 : 24;
        coefRegion3<3, 11, 3, 1, 0>(p.U3[1], p.W3[1], s, row0, rows, c0, Cg, sU, sW);
    } else if (t < 21) {
        int rel = t - 14, row0 = rel * 24, rows = (rel == 6) ? 21 : 24;
        coefRegion3<3, 13, 5, 4, 0>(p.U3[2], p.W3[2], s, row0, rows, c0, Cg, sU, sW);
    } else if (t < 23) {
        int rel = t - 21, row0 = rel * 24, rows = (rel == 1) ? 21 : 24;
        coefRegion3<2, 3, 1, 0, 165>(p.U2[0], p.W2[0], s, row0, rows, c0, Cg, sU, sW);
    } else if (t < 25) {
        int rel = t - 23, row0 = rel * 24, rows = (rel == 1) ? 21 : 24;
        coefRegion3<2, 2, 3, 1, 165>(p.U2[1], p.W2[1], s, row0, rows, c0, Cg, sU, sW);
    } else if (t < 27) {
        int rel = t - 25, row0 = rel * 24, rows = (rel == 1) ? 21 : 24;
        coefRegion3<2, 3, 5, 4, 165>(p.U2[2], p.W2[2], s, row0, rows, c0, Cg, sU, sW);
    } else if (t == 27) {
        coefRegion3<1, 1, 1, 0, 210>(p.U1[0], p.W1[0], s, 0, 9, c0, Cg, sU, sW);
    } else if (t == 28) {
        coefRegion3<1, 1, 3, 1, 210>(p.U1[1], p.W1[1], s, 0, 9, c0, Cg, sU, sW);
    } else {
        coefRegion3<1, 1, 5, 4, 210>(p.U1[2], p.W1[2], s, 0, 9, c0, Cg, sU, sW);
    }
}

// ---------------------------------------------------------------------------
// Kernel 2: evaluation, "split-plane uniform" scheme (round 8) + LICM fix.
// LDS page staged as [219][16] floats: {c0..3, c8, -, -, -, c4..7, c8, -,-,-}.
// 128 threads = 2 waves; BOTH waves process the same 256 nodes (4/thread);
// wave w reads its half-plane at uniform float offset w*8 -> ONE code path.
// Per monomial per wave: 1 ds_read_b128 + 1 ds_read_b32 + 4 muls + 20 FMA.
//
// ROUND-8 SPILL ROOT CAUSE: all coefficient LDS reads had loop-invariant
// addresses w.r.t. the node loop -> IR-level LICM hoisted all ~438 reads out
// of the loop (sched_barrier is machine-level; LICM ignores it) -> ~1100 live
// floats -> 256 VGPR + 1.28 GB scratch. FIX: opaque zero (`off0`) laundered
// through inline asm INSIDE the loop; every address derives from it, so no
// load is loop-invariant. Within an iteration, sched_barrier(0) after each
// bodyB keeps liveness <= ~10 monomials.
// ---------------------------------------------------------------------------
__device__ constexpr int pairIdx(int a, int b) {   // index among sorted pairs
    int s = 0;
    for (int t = 0; t < a; ++t) s += 9 - t;
    return s + (b - a);
}
__device__ constexpr int triBase(int a, int b) {   // first triple (a,b,*)
    int s = 0;
    for (int t = 0; t < a; ++t) s += (9 - t) * (10 - t) / 2;
    for (int t = a; t < b; ++t) s += 9 - t;
    return s;
}

template <int A, int B>
__device__ __forceinline__ void bodyB(const float* __restrict__ sP, int woff,
                                      const float (&x)[4][9],
                                      float4 (&oM)[4], float (&o8)[4]) {
    float xab[4];
#pragma unroll
    for (int u = 0; u < 4; ++u) xab[u] = x[u][A] * x[u][B];
    {   // S2 monomial
        constexpr int m = 165 + pairIdx(A, B);
        const float4 cm = *(const float4*)&sP[m * 16 + woff];
        const float  c8 = sP[m * 16 + 4 + woff];
#pragma unroll
        for (int u = 0; u < 4; ++u) { oM[u] += cm * xab[u]; o8[u] += c8 * xab[u]; }
    }
#pragma unroll
    for (int j = B; j < 9; ++j) {   // S3 monomials (j static after unroll)
        const int m = triBase(A, B) + (j - B);
        const float4 cm = *(const float4*)&sP[m * 16 + woff];
        const float  c8 = sP[m * 16 + 4 + woff];
#pragma unroll
        for (int u = 0; u < 4; ++u) {
            const float mn = xab[u] * x[u][j];
            oM[u] += cm * mn; o8[u] += c8 * mn;
        }
    }
}

template <int A, int B>
struct BChain {
    static __device__ __forceinline__ void run(const float* __restrict__ sP, int woff,
                                               const float (&x)[4][9],
                                               float4 (&oM)[4], float (&o8)[4]) {
        bodyB<A, B>(sP, woff, x, oM, o8);
        __builtin_amdgcn_sched_barrier(0);
        BChain<A, B + 1>::run(sP, woff, x, oM, o8);
    }
};
template <int A>
struct BChain<A, 9> {
    static __device__ __forceinline__ void run(const float*, int, const float (&)[4][9],
                                               float4 (&)[4], float (&)[4]) {}
};

template <int A>
__device__ __forceinline__ void bodyA(const float* __restrict__ sP, int woff,
                                      const float (&x)[4][9],
                                      float4 (&oM)[4], float (&o8)[4]) {
    {   // S1 monomial m = 210+A
        constexpr int m = 210 + A;
        const float4 cm = *(const float4*)&sP[m * 16 + woff];
        const float  c8 = sP[m * 16 + 4 + woff];
#pragma unroll
        for (int u = 0; u < 4; ++u) {
            const float xa = x[u][A];
            oM[u] += cm * xa; o8[u] += c8 * xa;
        }
    }
    __builtin_amdgcn_sched_barrier(0);
    BChain<A, A>::run(sP, woff, x, oM, o8);
}

__global__ __launch_bounds__(128, 1) void sc_eval_kernel(const float* __restrict__ nf,
                                                         const int* __restrict__ counts,
                                                         const int* __restrict__ lists,
                                                         const float* __restrict__ Cg,
                                                         float* __restrict__ out) {
    __shared__ __align__(16) float sP[219 * 16];
    const int s = blockIdx.x / C_CH;
    const int c = blockIdx.x % C_CH;
    const float* __restrict__ Cp = Cg + (size_t)(s * C_CH + c) * PAGE2;

    {   // restage 8KB page -> [219][16] split-plane layout
        const float4* Gv = (const float4*)Cp;
        for (int m = threadIdx.x; m < 219; m += 128) {
            const float4 v1 = Gv[m * 2];
            const float4 v2 = Gv[m * 2 + 1];
            const float  t  = Cp[MAIN_F + m];
            float4* L = (float4*)&sP[m * 16];
            L[0] = v1;                 // floats 0..3   = c0..c3
            L[2] = v2;                 // floats 8..11  = c4..c7
            sP[m * 16 + 4]  = t;       // c8 (wave0 plane)
            sP[m * 16 + 12] = t;       // c8 dup (wave1 plane)
        }
    }
    __syncthreads();

    const int cnt  = counts[s];
    const int wid  = threadIdx.x >> 6;       // wave id: 0 or 1 (uniform)
    const int lane = threadIdx.x & 63;

    for (int base = 0; base < cnt; base += 256) {
        // --- LICM blocker: opaque zero, redefined every iteration ---
        int off0 = 0;
        asm volatile("" : "+v"(off0));
        const int woff = wid * 8 + off0;     // all LDS addrs derive from off0

        int mm[4];
        float x[4][9];
#pragma unroll
        for (int u = 0; u < 4; ++u) {
            const int i = base + lane + 64 * u;          // both waves: same slots
            mm[u] = (i < cnt) ? lists[s * N_NODES + i] : -1;
            const float* xp = nf + ((long)(mm[u] < 0 ? 0 : mm[u]) * C_CH + c) * 9;
#pragma unroll
            for (int j = 0; j < 9; ++j) x[u][j] = xp[j];
        }

        float4 oM[4];
        float  o8[4];
#pragma unroll
        for (int u = 0; u < 4; ++u) { oM[u] = {0, 0, 0, 0}; o8[u] = 0.f; }

        bodyA<0>(sP, woff, x, oM, o8); __builtin_amdgcn_sched_barrier(0);
        bodyA<1>(sP, woff, x, oM, o8); __builtin_amdgcn_sched_barrier(0);
        bodyA<2>(sP, woff, x, oM, o8); __builtin_amdgcn_sched_barrier(0);
        bodyA<3>(sP, woff, x, oM, o8); __builtin_amdgcn_sched_barrier(0);
        bodyA<4>(sP, woff, x, oM, o8); __builtin_amdgcn_sched_barrier(0);
        bodyA<5>(sP, woff, x, oM, o8); __builtin_amdgcn_sched_barrier(0);
        bodyA<6>(sP, woff, x, oM, o8); __builtin_amdgcn_sched_barrier(0);
        bodyA<7>(sP, woff, x, oM, o8); __builtin_amdgcn_sched_barrier(0);
        bodyA<8>(sP, woff, x, oM, o8);

        if (wid == 0) {
#pragma unroll
            for (int u = 0; u < 4; ++u) {
                if (mm[u] >= 0) {
                    float* op = out + ((long)mm[u] * C_CH + c) * 9;
                    op[0] = oM[u].x; op[1] = oM[u].y; op[2] = oM[u].z; op[3] = oM[u].w;
                    op[8] = o8[u];
                }
            }
        } else {
#pragma unroll
            for (int u = 0; u < 4; ++u) {
                if (mm[u] >= 0) {
                    float* op = out + ((long)mm[u] * C_CH + c) * 9;
                    op[4] = oM[u].x; op[5] = oM[u].y; op[6] = oM[u].z; op[7] = oM[u].w;
                }
            }
        }
    }
}

// ---------------------------------------------------------------------------
// Fallback path (round-0 verified kernels) in case ws_size is too small.
// ---------------------------------------------------------------------------
__global__ __launch_bounds__(1024) void bucket_kernel(const int* __restrict__ index,
                                                      int* __restrict__ counts,
                                                      int* __restrict__ lists) {
    __shared__ int sc[N_SPEC];
    const int tid = threadIdx.x;
    if (tid < N_SPEC) sc[tid] = 0;
    __syncthreads();
    for (int n = tid; n < N_NODES; n += blockDim.x) {
        int s = index[n];
        int pos = atomicAdd(&sc[s], 1);
        lists[s * N_NODES + pos] = n;
    }
    __syncthreads();
    if (tid < N_SPEC) counts[tid] = sc[tid];
}

template <int NAB, int MUL, int IRD, int IOFF>
__device__ inline void buildC(const float* __restrict__ u, const float* __restrict__ w,
                              int s, int c, float* __restrict__ sMain, float* __restrict__ sB) {
    const int tid = threadIdx.x;
    const float* wp = w + (s * MUL) * C_CH + c;
    for (int e = tid; e < NAB * IRD; e += 128) {
        int abj = e / IRD;
        int il  = e - abj * IRD;
        const float* up = u + (abj * MUL) * IRD + il;
        float acc = 0.f;
#pragma unroll
        for (int k = 0; k < MUL; ++k)
            acc += up[k * IRD] * wp[k * C_CH];
        int i = IOFF + il;
        if (i < 8) sMain[abj * 8 + i] = acc;
        else       sB[abj] = acc;
    }
}

__device__ inline float selx(const float x[9], int a) {
    float r = x[0];
    r = (a == 1) ? x[1] : r; r = (a == 2) ? x[2] : r; r = (a == 3) ? x[3] : r;
    r = (a == 4) ? x[4] : r; r = (a == 5) ? x[5] : r; r = (a == 6) ? x[6] : r;
    r = (a == 7) ? x[7] : r; r = (a == 8) ? x[8] : r;
    return r;
}

__global__ __launch_bounds__(128) void sc_kernel(const float* __restrict__ nf,
                                                 const int* __restrict__ counts,
                                                 const int* __restrict__ lists,
                                                 Params p,
                                                 float* __restrict__ out) {
    __shared__ __align__(16) float sC3[729 * 8];
    __shared__ float sC3b[729];
    __shared__ __align__(16) float sC2[81 * 8];
    __shared__ float sC2b[81];
    __shared__ __align__(16) float sC1[9 * 8];
    __shared__ float sC1b[9];

    const int s = blockIdx.x % N_SPEC;
    const int c = blockIdx.x / N_SPEC;
    const int tid = threadIdx.x;

    buildC<729, 10, 1, 0>(p.U3[0], p.W3[0], s, c, sC3, sC3b);
    buildC<729, 11, 3, 1>(p.U3[1], p.W3[1], s, c, sC3, sC3b);
    buildC<729, 13, 5, 4>(p.U3[2], p.W3[2], s, c, sC3, sC3b);
    buildC<81, 3, 1, 0>(p.U2[0], p.W2[0], s, c, sC2, sC2b);
    buildC<81, 2, 3, 1>(p.U2[1], p.W2[1], s, c, sC2, sC2b);
    buildC<81, 3, 5, 4>(p.U2[2], p.W2[2], s, c, sC2, sC2b);
    buildC<9, 1, 1, 0>(p.U1[0], p.W1[0], s, c, sC1, sC1b);
    buildC<9, 1, 3, 1>(p.U1[1], p.W1[1], s, c, sC1, sC1b);
    buildC<9, 1, 5, 4>(p.U1[2], p.W1[2], s, c, sC1, sC1b);
    __syncthreads();

    const int cnt = counts[s];
    const float4* C3v = (const float4*)sC3;
    const float4* C2v = (const float4*)sC2;
    const float4* C1v = (const float4*)sC1;

    for (int base = 0; base < cnt; base += 256) {
        const int i0 = base + tid;
        const int i1 = base + 128 + tid;
        const int m0 = (i0 < cnt) ? lists[s * N_NODES + i0] : -1;
        const int m1 = (i1 < cnt) ? lists[s * N_NODES + i1] : -1;

        const float* x0p = nf + ((long)(m0 < 0 ? 0 : m0) * C_CH + c) * 9;
        const float* x1p = nf + ((long)(m1 < 0 ? 0 : m1) * C_CH + c) * 9;
        float x0[9], x1[9];
#pragma unroll
        for (int j = 0; j < 9; ++j) { x0[j] = x0p[j]; x1[j] = x1p[j]; }

        float4 o0a = {0, 0, 0, 0}, o0b = {0, 0, 0, 0};
        float4 o1a = {0, 0, 0, 0}, o1b = {0, 0, 0, 0};
        float o08 = 0.f, o18 = 0.f;

#pragma unroll 1
        for (int a = 0; a < 9; ++a) {
            const float xa0 = selx(x0, a);
            const float xa1 = selx(x1, a);
            const float4 c1a = C1v[a * 2], c1b = C1v[a * 2 + 1];
            const float  c18 = sC1b[a];
            float4 q0a = c1a, q0b = c1b; float q08 = c18;
            float4 q1a = c1a, q1b = c1b; float q18 = c18;
#pragma unroll
            for (int b = 0; b < 9; ++b) {
                const int ab = a * 9 + b;
                const float4 c2a = C2v[ab * 2], c2b = C2v[ab * 2 + 1];
                const float  c28 = sC2b[ab];
                float4 t0a = c2a, t0b = c2b; float t08 = c28;
                float4 t1a = c2a, t1b = c2b; float t18 = c28;
#pragma unroll
                for (int j = 0; j < 9; ++j) {
                    const int abj = ab * 9 + j;
                    const float4 ca = C3v[abj * 2];
                    const float4 cb = C3v[abj * 2 + 1];
                    const float  c8 = sC3b[abj];
                    t0a += ca * x0[j]; t0b += cb * x0[j]; t08 += c8 * x0[j];
                    t1a += ca * x1[j]; t1b += cb * x1[j]; t18 += c8 * x1[j];
                }
                q0a += t0a * x0[b]; q0b += t0b * x0[b]; q08 += t08 * x0[b];
                q1a += t1a * x1[b]; q1b += t1b * x1[b]; q18 += t18 * x1[b];
            }
            o0a += q0a * xa0; o0b += q0b * xa0; o08 += q08 * xa0;
            o1a += q1a * xa1; o1b += q1b * xa1; o18 += q18 * xa1;
        }

        if (m0 >= 0) {
            float* op = out + ((long)m0 * C_CH + c) * 9;
            op[0] = o0a.x; op[1] = o0a.y; op[2] = o0a.z; op[3] = o0a.w;
            op[4] = o0b.x; op[5] = o0b.y; op[6] = o0b.z; op[7] = o0b.w;
            op[8] = o08;
        }
        if (m1 >= 0) {
            float* op = out + ((long)m1 * C_CH + c) * 9;
            op[0] = o1a.x; op[1] = o1a.y; op[2] = o1a.z; op[3] = o1a.w;
            op[4] = o1b.x; op[5] = o1b.y; op[6] = o1b.z; op[7] = o1b.w;
            op[8] = o18;
        }
    }
}

// ---------------------------------------------------------------------------
extern "C" void kernel_launch(void* const* d_in, const int* in_sizes, int n_in,
                              void* d_out, int out_size, void* d_ws, size_t ws_size,
                              hipStream_t stream) {
    const float* nf   = (const float*)d_in[0];
    const int* index  = (const int*)d_in[1];

    Params p;
    p.U3[0] = (const float*)d_in[2];  p.W3[0] = (const float*)d_in[3];
    p.U3[1] = (const float*)d_in[4];  p.W3[1] = (const float*)d_in[5];
    p.U3[2] = (const float*)d_in[6];  p.W3[2] = (const float*)d_in[7];
    p.U2[0] = (const float*)d_in[8];  p.W2[0] = (const float*)d_in[9];
    p.U2[1] = (const float*)d_in[10]; p.W2[1] = (const float*)d_in[11];
    p.U2[2] = (const float*)d_in[12]; p.W2[2] = (const float*)d_in[13];
    p.U1[0] = (const float*)d_in[14]; p.W1[0] = (const float*)d_in[15];
    p.U1[1] = (const float*)d_in[16]; p.W1[1] = (const float*)d_in[17];
    p.U1[2] = (const float*)d_in[18]; p.W1[2] = (const float*)d_in[19];

    int* counts = (int*)d_ws;        // 16 ints
    int* lists  = (int*)d_ws + 16;   // 10 * 2048 ints, ends at 81,984 B

    if (ws_size >= (size_t)CG_OFF_B + CG_BYTES) {
        float* Cg = (float*)((char*)d_ws + CG_OFF_B);
        prep_kernel<<<N_SPEC * 120 + 1, 128, 0, stream>>>(p, index, counts, lists, Cg);
        sc_eval_kernel<<<N_SPEC * C_CH, 128, 0, stream>>>(nf, counts, lists, Cg,
                                                          (float*)d_out);
    } else {
        bucket_kernel<<<1, 1024, 0, stream>>>(index, counts, lists);
        sc_kernel<<<N_SPEC * C_CH, 128, 0, stream>>>(nf, counts, lists, p,
                                                     (float*)d_out);
    }
}

// Round 10
// 189.834 us; speedup vs baseline: 6.8615x; 4.7334x over previous
//
#include <hip/hip_runtime.h>

#define N_NODES 2048
#define C_CH    128
#define N_SPEC  10

// --- symmetric-reduced coefficient page per (species, channel) ---------------
// Layout: main[219][8] (monomial-major, i=0..7) | tail[219] (i==8), pad to 2048.
// Monomial order: m=0..164 sorted triples a<=b<=j (lex), 165..209 sorted pairs
// a<=b (lex), 210..218 singles a.
#define PAGE2   2048
#define MAIN_F  1752          // 219*8

#define CG_OFF_B  (256 * 1024)
#define CG_BYTES  ((size_t)N_SPEC * C_CH * PAGE2 * 4)

struct Params {
    const float* U3[3]; const float* W3[3];
    const float* U2[3]; const float* W2[3];
    const float* U1[3]; const float* W1[3];
};

// ---------------------------------------------------------------------------
// Kernel 1 (fused prep) — verified rounds 7/9 (MUL=1 fix included).
// Blocks 0..1199 build coefficient pages; block 1200 buckets nodes by species.
// ---------------------------------------------------------------------------
template <int ORD, int MUL, int IRD, int IOFF, int MOFF>
__device__ inline void coefRegion3(const float* __restrict__ u,
                                   const float* __restrict__ W,
                                   int s, int row0, int rows, int c0,
                                   float* __restrict__ Cg,
                                   float* __restrict__ sU, float* __restrict__ sW) {
    const int tid = threadIdx.x;
    const int mi  = MUL * IRD;
    const int nfl = rows * mi;
    for (int f = tid; f < nfl; f += 128) {
        const int rr  = f / mi;
        const int rem = f - rr * mi;
        const int n   = row0 + rr;
        float acc;
        if (ORD == 3) {
            int nn = n, aa = 0;
            while (true) { int ca = (9 - aa) * (10 - aa) / 2; if (nn < ca) break; nn -= ca; ++aa; }
            int bb = aa;
            while (true) { int cb = 9 - bb; if (nn < cb) break; nn -= cb; ++bb; }
            const int jj = bb + nn;
            int L[6];
            L[0] = (aa * 9 + bb) * 9 + jj; L[1] = (aa * 9 + jj) * 9 + bb;
            L[2] = (bb * 9 + aa) * 9 + jj; L[3] = (bb * 9 + jj) * 9 + aa;
            L[4] = (jj * 9 + aa) * 9 + bb; L[5] = (jj * 9 + bb) * 9 + aa;
            acc = 0.f;
            for (int m = 0; m < 6; ++m) {
                bool dup = false;
                for (int q = 0; q < m; ++q) dup = dup || (L[q] == L[m]);
                if (!dup) acc += u[L[m] * mi + rem];
            }
        } else if (ORD == 2) {
            int nn = n, aa = 0;
            while (true) { int cb = 9 - aa; if (nn < cb) break; nn -= cb; ++aa; }
            const int bb = aa + nn;
            acc = u[(aa * 9 + bb) * mi + rem];
            if (aa != bb) acc += u[(bb * 9 + aa) * mi + rem];
        } else {
            acc = u[n * mi + rem];
        }
        sU[f] = acc;
    }
    for (int idx = tid; idx < MUL * 32; idx += 128) {
        const int k = idx >> 5, cc = idx & 31;
        sW[idx] = W[(s * MUL + k) * C_CH + c0 + cc];
    }
    __syncthreads();

    const int nel = rows * IRD;
    for (int f = tid; f < nel; f += 128) {
        const int rr = f / IRD;
        const int il = f - rr * IRD;
        float uv[MUL];
#pragma unroll
        for (int k = 0; k < MUL; ++k) uv[k] = sU[(rr * MUL + k) * IRD + il];
        const int m = MOFF + row0 + rr;
        const int i = IOFF + il;
        const int off = (i < 8) ? (m * 8 + i) : (MAIN_F + m);
        for (int cc = 0; cc < 32; ++cc) {
            float acc = 0.f;
#pragma unroll
            for (int k = 0; k < MUL; ++k) acc += uv[k] * sW[k * 32 + cc];
            Cg[(size_t)(s * C_CH + c0 + cc) * PAGE2 + off] = acc;
        }
    }
}

__global__ __launch_bounds__(128) void prep_kernel(Params p, const int* __restrict__ index,
                                                   int* __restrict__ counts,
                                                   int* __restrict__ lists,
                                                   float* __restrict__ Cg) {
    const int bx = blockIdx.x;
    if (bx == N_SPEC * 120) {   // --- bucket block ---
        __shared__ int sc[N_SPEC];
        const int tid = threadIdx.x;
        if (tid < N_SPEC) sc[tid] = 0;
        __syncthreads();
        for (int n = tid; n < N_NODES; n += 128) {
            int s = index[n];
            int pos = atomicAdd(&sc[s], 1);
            lists[s * N_NODES + pos] = n;
        }
        __syncthreads();
        if (tid < N_SPEC) counts[tid] = sc[tid];
        return;
    }
    __shared__ float sU[1560];
    __shared__ float sW[13 * 32];
    const int s   = bx / 120;
    const int rem = bx % 120;
    const int t   = rem / 4;
    const int c0  = (rem % 4) * 32;

    if (t < 7) {
        int rel = t, row0 = rel * 24, rows = (rel == 6) ? 21 : 24;
        coefRegion3<3, 10, 1, 0, 0>(p.U3[0], p.W3[0], s, row0, rows, c0, Cg, sU, sW);
    } else if (t < 14) {
        int rel = t - 7, row0 = rel * 24, rows = (rel == 6) ? 21 : 24;
        coefRegion3<3, 11, 3, 1, 0>(p.U3[1], p.W3[1], s, row0, rows, c0, Cg, sU, sW);
    } else if (t < 21) {
        int rel = t - 14, row0 = rel * 24, rows = (rel == 6) ? 21 : 24;
        coefRegion3<3, 13, 5, 4, 0>(p.U3[2], p.W3[2], s, row0, rows, c0, Cg, sU, sW);
    } else if (t < 23) {
        int rel = t - 21, row0 = rel * 24, rows = (rel == 1) ? 21 : 24;
        coefRegion3<2, 3, 1, 0, 165>(p.U2[0], p.W2[0], s, row0, rows, c0, Cg, sU, sW);
    } else if (t < 25) {
        int rel = t - 23, row0 = rel * 24, rows = (rel == 1) ? 21 : 24;
        coefRegion3<2, 2, 3, 1, 165>(p.U2[1], p.W2[1], s, row0, rows, c0, Cg, sU, sW);
    } else if (t < 27) {
        int rel = t - 25, row0 = rel * 24, rows = (rel == 1) ? 21 : 24;
        coefRegion3<2, 3, 5, 4, 165>(p.U2[2], p.W2[2], s, row0, rows, c0, Cg, sU, sW);
    } else if (t == 27) {
        coefRegion3<1, 1, 1, 0, 210>(p.U1[0], p.W1[0], s, 0, 9, c0, Cg, sU, sW);
    } else if (t == 28) {
        coefRegion3<1, 1, 3, 1, 210>(p.U1[1], p.W1[1], s, 0, 9, c0, Cg, sU, sW);
    } else {
        coefRegion3<1, 1, 5, 4, 210>(p.U1[2], p.W1[2], s, 0, 9, c0, Cg, sU, sW);
    }
}

// dynamic index into a register array: cndmask chain (selector wave-uniform)
__device__ inline float selx(const float x[9], int a) {
    float r = x[0];
    r = (a == 1) ? x[1] : r; r = (a == 2) ? x[2] : r; r = (a == 3) ? x[3] : r;
    r = (a == 4) ? x[4] : r; r = (a == 5) ? x[5] : r; r = (a == 6) ? x[6] : r;
    r = (a == 7) ? x[7] : r; r = (a == 8) ? x[8] : r;
    return r;
}

// ---------------------------------------------------------------------------
// Kernel 2: evaluation — round-4 verified structure (rolled loops, pointer
// streams, 128 thr, 2 nodes/thread; compiled to 24 VGPR / no spill / 65 us)
// + explicit DEPTH-1 SOFTWARE PREFETCH on the three contiguous coefficient
// streams (triples p3/t3, pairs p2/t2, singles p1/t1). Round-4's measured
// stall was ~85% exposed ds_read latency (serial load->wait->FMA per
// monomial); the rotation (c3 <- n3 etc.) issues monomial m+1's loads before
// monomial m's FMAs, overlapping ~120cy latency with ~72cy of compute.
// Prefetch past stream end reads the next region's floats (in-bounds within
// the 8KB page) and is discarded. All loops #pragma unroll 1: stays in the
// proven no-spill regime (rounds 3/7/8/9: every static unroll spilled).
// ---------------------------------------------------------------------------
__global__ __launch_bounds__(128) void sc_eval_kernel(const float* __restrict__ nf,
                                                      const int* __restrict__ counts,
                                                      const int* __restrict__ lists,
                                                      const float* __restrict__ Cg,
                                                      float* __restrict__ out) {
    __shared__ __align__(16) float sP[PAGE2];
    const int s = blockIdx.x / C_CH;   // 128 consecutive blocks share a species
    const int c = blockIdx.x % C_CH;
    const float* __restrict__ Cp = Cg + (size_t)(s * C_CH + c) * PAGE2;

    {   // flat coalesced 8 KB stage: 128 threads x 4 float4
        const float4* g = (const float4*)Cp;
        float4* l = (float4*)sP;
#pragma unroll
        for (int q = 0; q < 4; ++q) l[threadIdx.x + 128 * q] = g[threadIdx.x + 128 * q];
    }
    __syncthreads();

    const int cnt = counts[s];
    const float4* __restrict__ Cv = (const float4*)sP;
    const float*  __restrict__ Ct = sP + MAIN_F;

    for (int base = 0; base < cnt; base += 256) {
        const int i0 = base + threadIdx.x;
        const int i1 = base + 128 + threadIdx.x;
        const int m0 = (i0 < cnt) ? lists[s * N_NODES + i0] : -1;
        const int m1 = (i1 < cnt) ? lists[s * N_NODES + i1] : -1;

        const float* x0p = nf + ((long)(m0 < 0 ? 0 : m0) * C_CH + c) * 9;
        const float* x1p = nf + ((long)(m1 < 0 ? 0 : m1) * C_CH + c) * 9;
        float x0[9], x1[9];
#pragma unroll
        for (int j = 0; j < 9; ++j) { x0[j] = x0p[j]; x1[j] = x1p[j]; }

        float4 o0a = {0, 0, 0, 0}, o0b = {0, 0, 0, 0};
        float4 o1a = {0, 0, 0, 0}, o1b = {0, 0, 0, 0};
        float o08 = 0.f, o18 = 0.f;

        // stream pointers (contiguous across the whole a/b/j nest)
        const float4* p3 = Cv;            const float* t3 = Ct;
        const float4* p2 = Cv + 165 * 2;  const float* t2 = Ct + 165;
        const float4* p1 = Cv + 210 * 2;  const float* t1 = Ct + 210;

        // preload stream heads
        float4 c3a = p3[0], c3b = p3[1]; float c38 = t3[0];
        float4 c2a = p2[0], c2b = p2[1]; float c28 = t2[0];
        float4 c1a = p1[0], c1b = p1[1]; float c18 = t1[0];

#pragma unroll 1
        for (int a = 0; a < 9; ++a) {
            const float xa0 = selx(x0, a);
            const float xa1 = selx(x1, a);
            {   // S1 monomial (prefetch next single, then use current)
                const float4 n1a = p1[2], n1b = p1[3]; const float n18 = t1[1];
                o0a += c1a * xa0; o0b += c1b * xa0; o08 += c18 * xa0;
                o1a += c1a * xa1; o1b += c1b * xa1; o18 += c18 * xa1;
                c1a = n1a; c1b = n1b; c18 = n18; p1 += 2; ++t1;
            }
#pragma unroll 1
            for (int b = a; b < 9; ++b) {
                const float xb0 = selx(x0, b) * xa0;
                const float xb1 = selx(x1, b) * xa1;
                {   // S2 monomial (prefetch next pair, then use current)
                    const float4 n2a = p2[2], n2b = p2[3]; const float n28 = t2[1];
                    o0a += c2a * xb0; o0b += c2b * xb0; o08 += c28 * xb0;
                    o1a += c2a * xb1; o1b += c2b * xb1; o18 += c28 * xb1;
                    c2a = n2a; c2b = n2b; c28 = n28; p2 += 2; ++t2;
                }
#pragma unroll 1
                for (int j = b; j < 9; ++j) {   // S3 monomials
                    const float4 n3a = p3[2], n3b = p3[3]; const float n38 = t3[1];
                    const float mn0 = selx(x0, j) * xb0;
                    const float mn1 = selx(x1, j) * xb1;
                    o0a += c3a * mn0; o0b += c3b * mn0; o08 += c38 * mn0;
                    o1a += c3a * mn1; o1b += c3b * mn1; o18 += c38 * mn1;
                    c3a = n3a; c3b = n3b; c38 = n38; p3 += 2; ++t3;
                }
            }
        }

        if (m0 >= 0) {
            float* op = out + ((long)m0 * C_CH + c) * 9;
            op[0] = o0a.x; op[1] = o0a.y; op[2] = o0a.z; op[3] = o0a.w;
            op[4] = o0b.x; op[5] = o0b.y; op[6] = o0b.z; op[7] = o0b.w;
            op[8] = o08;
        }
        if (m1 >= 0) {
            float* op = out + ((long)m1 * C_CH + c) * 9;
            op[0] = o1a.x; op[1] = o1a.y; op[2] = o1a.z; op[3] = o1a.w;
            op[4] = o1b.x; op[5] = o1b.y; op[6] = o1b.z; op[7] = o1b.w;
            op[8] = o18;
        }
    }
}

// ---------------------------------------------------------------------------
// Fallback path (round-0 verified kernels) in case ws_size is too small.
// ---------------------------------------------------------------------------
__global__ __launch_bounds__(1024) void bucket_kernel(const int* __restrict__ index,
                                                      int* __restrict__ counts,
                                                      int* __restrict__ lists) {
    __shared__ int sc[N_SPEC];
    const int tid = threadIdx.x;
    if (tid < N_SPEC) sc[tid] = 0;
    __syncthreads();
    for (int n = tid; n < N_NODES; n += blockDim.x) {
        int s = index[n];
        int pos = atomicAdd(&sc[s], 1);
        lists[s * N_NODES + pos] = n;
    }
    __syncthreads();
    if (tid < N_SPEC) counts[tid] = sc[tid];
}

template <int NAB, int MUL, int IRD, int IOFF>
__device__ inline void buildC(const float* __restrict__ u, const float* __restrict__ w,
                              int s, int c, float* __restrict__ sMain, float* __restrict__ sB) {
    const int tid = threadIdx.x;
    const float* wp = w + (s * MUL) * C_CH + c;
    for (int e = tid; e < NAB * IRD; e += 128) {
        int abj = e / IRD;
        int il  = e - abj * IRD;
        const float* up = u + (abj * MUL) * IRD + il;
        float acc = 0.f;
#pragma unroll
        for (int k = 0; k < MUL; ++k)
            acc += up[k * IRD] * wp[k * C_CH];
        int i = IOFF + il;
        if (i < 8) sMain[abj * 8 + i] = acc;
        else       sB[abj] = acc;
    }
}

__global__ __launch_bounds__(128) void sc_kernel(const float* __restrict__ nf,
                                                 const int* __restrict__ counts,
                                                 const int* __restrict__ lists,
                                                 Params p,
                                                 float* __restrict__ out) {
    __shared__ __align__(16) float sC3[729 * 8];
    __shared__ float sC3b[729];
    __shared__ __align__(16) float sC2[81 * 8];
    __shared__ float sC2b[81];
    __shared__ __align__(16) float sC1[9 * 8];
    __shared__ float sC1b[9];

    const int s = blockIdx.x % N_SPEC;
    const int c = blockIdx.x / N_SPEC;
    const int tid = threadIdx.x;

    buildC<729, 10, 1, 0>(p.U3[0], p.W3[0], s, c, sC3, sC3b);
    buildC<729, 11, 3, 1>(p.U3[1], p.W3[1], s, c, sC3, sC3b);
    buildC<729, 13, 5, 4>(p.U3[2], p.W3[2], s, c, sC3, sC3b);
    buildC<81, 3, 1, 0>(p.U2[0], p.W2[0], s, c, sC2, sC2b);
    buildC<81, 2, 3, 1>(p.U2[1], p.W2[1], s, c, sC2, sC2b);
    buildC<81, 3, 5, 4>(p.U2[2], p.W2[2], s, c, sC2, sC2b);
    buildC<9, 1, 1, 0>(p.U1[0], p.W1[0], s, c, sC1, sC1b);
    buildC<9, 1, 3, 1>(p.U1[1], p.W1[1], s, c, sC1, sC1b);
    buildC<9, 1, 5, 4>(p.U1[2], p.W1[2], s, c, sC1, sC1b);
    __syncthreads();

    const int cnt = counts[s];
    const float4* C3v = (const float4*)sC3;
    const float4* C2v = (const float4*)sC2;
    const float4* C1v = (const float4*)sC1;

    for (int base = 0; base < cnt; base += 256) {
        const int i0 = base + tid;
        const int i1 = base + 128 + tid;
        const int m0 = (i0 < cnt) ? lists[s * N_NODES + i0] : -1;
        const int m1 = (i1 < cnt) ? lists[s * N_NODES + i1] : -1;

        const float* x0p = nf + ((long)(m0 < 0 ? 0 : m0) * C_CH + c) * 9;
        const float* x1p = nf + ((long)(m1 < 0 ? 0 : m1) * C_CH + c) * 9;
        float x0[9], x1[9];
#pragma unroll
        for (int j = 0; j < 9; ++j) { x0[j] = x0p[j]; x1[j] = x1p[j]; }

        float4 o0a = {0, 0, 0, 0}, o0b = {0, 0, 0, 0};
        float4 o1a = {0, 0, 0, 0}, o1b = {0, 0, 0, 0};
        float o08 = 0.f, o18 = 0.f;

#pragma unroll 1
        for (int a = 0; a < 9; ++a) {
            const float xa0 = selx(x0, a);
            const float xa1 = selx(x1, a);
            const float4 c1a = C1v[a * 2], c1b = C1v[a * 2 + 1];
            const float  c18 = sC1b[a];
            float4 q0a = c1a, q0b = c1b; float q08 = c18;
            float4 q1a = c1a, q1b = c1b; float q18 = c18;
#pragma unroll
            for (int b = 0; b < 9; ++b) {
                const int ab = a * 9 + b;
                const float4 c2a = C2v[ab * 2], c2b = C2v[ab * 2 + 1];
                const float  c28 = sC2b[ab];
                float4 t0a = c2a, t0b = c2b; float t08 = c28;
                float4 t1a = c2a, t1b = c2b; float t18 = c28;
#pragma unroll
                for (int j = 0; j < 9; ++j) {
                    const int abj = ab * 9 + j;
                    const float4 ca = C3v[abj * 2];
                    const float4 cb = C3v[abj * 2 + 1];
                    const float  c8 = sC3b[abj];
                    t0a += ca * x0[j]; t0b += cb * x0[j]; t08 += c8 * x0[j];
                    t1a += ca * x1[j]; t1b += cb * x1[j]; t18 += c8 * x1[j];
                }
                q0a += t0a * x0[b]; q0b += t0b * x0[b]; q08 += t08 * x0[b];
                q1a += t1a * x1[b]; q1b += t1b * x1[b]; q18 += t18 * x1[b];
            }
            o0a += q0a * xa0; o0b += q0b * xa0; o08 += q08 * xa0;
            o1a += q1a * xa1; o1b += q1b * xa1; o18 += q18 * xa1;
        }

        if (m0 >= 0) {
            float* op = out + ((long)m0 * C_CH + c) * 9;
            op[0] = o0a.x; op[1] = o0a.y; op[2] = o0a.z; op[3] = o0a.w;
            op[4] = o0b.x; op[5] = o0b.y; op[6] = o0b.z; op[7] = o0b.w;
            op[8] = o08;
        }
        if (m1 >= 0) {
            float* op = out + ((long)m1 * C_CH + c) * 9;
            op[0] = o1a.x; op[1] = o1a.y; op[2] = o1a.z; op[3] = o1a.w;
            op[4] = o1b.x; op[5] = o1b.y; op[6] = o1b.z; op[7] = o1b.w;
            op[8] = o18;
        }
    }
}

// ---------------------------------------------------------------------------
extern "C" void kernel_launch(void* const* d_in, const int* in_sizes, int n_in,
                              void* d_out, int out_size, void* d_ws, size_t ws_size,
                              hipStream_t stream) {
    const float* nf   = (const float*)d_in[0];
    const int* index  = (const int*)d_in[1];

    Params p;
    p.U3[0] = (const float*)d_in[2];  p.W3[0] = (const float*)d_in[3];
    p.U3[1] = (const float*)d_in[4];  p.W3[1] = (const float*)d_in[5];
    p.U3[2] = (const float*)d_in[6];  p.W3[2] = (const float*)d_in[7];
    p.U2[0] = (const float*)d_in[8];  p.W2[0] = (const float*)d_in[9];
    p.U2[1] = (const float*)d_in[10]; p.W2[1] = (const float*)d_in[11];
    p.U2[2] = (const float*)d_in[12]; p.W2[2] = (const float*)d_in[13];
    p.U1[0] = (const float*)d_in[14]; p.W1[0] = (const float*)d_in[15];
    p.U1[1] = (const float*)d_in[16]; p.W1[1] = (const float*)d_in[17];
    p.U1[2] = (const float*)d_in[18]; p.W1[2] = (const float*)d_in[19];

    int* counts = (int*)d_ws;        // 16 ints
    int* lists  = (int*)d_ws + 16;   // 10 * 2048 ints, ends at 81,984 B

    if (ws_size >= (size_t)CG_OFF_B + CG_BYTES) {
        float* Cg = (float*)((char*)d_ws + CG_OFF_B);
        prep_kernel<<<N_SPEC * 120 + 1, 128, 0, stream>>>(p, index, counts, lists, Cg);
        sc_eval_kernel<<<N_SPEC * C_CH, 128, 0, stream>>>(nf, counts, lists, Cg,
                                                          (float*)d_out);
    } else {
        bucket_kernel<<<1, 1024, 0, stream>>>(index, counts, lists);
        sc_kernel<<<N_SPEC * C_CH, 128, 0, stream>>>(nf, counts, lists, p,
                                                     (float*)d_out);
    }
}